// Round 6
// baseline (273.503 us; speedup 1.0000x reference)
//
#include <hip/hip_runtime.h>
#include <hip/hip_bf16.h>
#include <cstdint>

// Problem constants (reference: N=16384, F=1024, H=256)
#define NR 16384
#define NF 1024
#define NH 256

typedef __bf16 bf16x8 __attribute__((ext_vector_type(8)));
typedef float f32x4 __attribute__((ext_vector_type(4)));
typedef unsigned short us8 __attribute__((ext_vector_type(8)));

static __device__ __forceinline__ unsigned short f2bf(float f) {
    unsigned u = __float_as_uint(f);
    u += 0x7FFFu + ((u >> 16) & 1u);   // RNE
    return (unsigned short)(u >> 16);
}
static __device__ __forceinline__ unsigned cvt2(float a, float b) {
    return ((unsigned)f2bf(b) << 16) | (unsigned)f2bf(a);
}

// ---------------------------------------------------------------------------
// prep: zero the 1 KB accumulator header + transpose We->WeT, Wd->WdT (bf16)
// 512 blocks: 0..255 = We tiles, 256..511 = Wd tiles
// ---------------------------------------------------------------------------
__global__ __launch_bounds__(256) void prep_kernel(
    const float* __restrict__ We, const float* __restrict__ Wd,
    unsigned short* __restrict__ WeT, unsigned short* __restrict__ WdT,
    float* __restrict__ hdr) {
    int b = blockIdx.x;
    if (b == 0 && threadIdx.x < 160) hdr[threadIdx.x] = 0.f;
    __shared__ float tile[32][33];
    const float* src; unsigned short* dst; int R, C, bx, by;
    if (b < 256) { src = We; dst = WeT; R = 1024; C = 256; bx = b & 7;  by = b >> 3; }
    else { b -= 256; src = Wd; dst = WdT; R = 256; C = 1024; bx = b & 31; by = b >> 5; }
    const int c0 = bx * 32, r0 = by * 32, t = threadIdx.x;
#pragma unroll
    for (int p = 0; p < 4; p++) {
        int idx = t + 256 * p;
        int r = idx >> 5, c = idx & 31;
        tile[r][c] = src[(size_t)(r0 + r) * C + c0 + c];
    }
    __syncthreads();
#pragma unroll
    for (int p = 0; p < 4; p++) {
        int idx = t + 256 * p;
        int rr = idx & 31, cc = idx >> 5;
        dst[(size_t)(c0 + cc) * R + r0 + rr] = f2bf(tile[rr][cc]);
    }
}

// ---------------------------------------------------------------------------
// FUSED, barrier-free K-loops. Per 32-row m-strip (grid 512 x 512 thr):
//  phase 1: g = X @ We + be; A and B fragments loaded DIRECTLY from global
//           (per-lane addresses == MFMA fragment layout; no LDS, no syncs).
//           Critic c fused; g -> swizzled LDS tile (one barrier total).
//  phase 2: rec = g @ Wd + bd; Wd fragments direct from L2; MSE vs X (L3).
// Header: hdr[0..63] mse cells, [64..127] pair cells, [128] ticket, [129] cntP
// ---------------------------------------------------------------------------
__global__ __launch_bounds__(512, 4) void fused_kernel(
    const float* __restrict__ X, const unsigned short* __restrict__ WeT,
    const unsigned short* __restrict__ WdT,
    const float* __restrict__ be, const float* __restrict__ bd,
    const float* __restrict__ Wc, const int* __restrict__ s, const int* __restrict__ pv,
    float* __restrict__ cpart, float* __restrict__ hdr) {
    __shared__ unsigned short gs[32 * 256];   // 16 KB, xor-swizzled (slot^m)
    __shared__ float credu[8][32];
    __shared__ float msred[8];
    const int t = threadIdx.x;
    const int m0 = blockIdx.x * 32;
    const int w = t >> 6, lane = t & 63, q = lane >> 4, li = lane & 15;
    const int nw = w * 32;   // phase-1 wave n-slice [nw, nw+32)

    // protected-row count (wave 0 only, one atomic per block)
    if (w == 0) {
        int pp = (lane < 32) ? (s[m0 + lane] == pv[0] ? 1 : 0) : 0;
        unsigned long long mb = __ballot(pp != 0);
        if (lane == 0) atomicAdd((int*)(hdr + 129), (int)__popcll(mb));
    }

    // ---------------- phase 1: X @ We (K=1024, no barriers) ----------------
    const float* A0 = X + (size_t)(m0 + li) * NF + q * 8;
    const float* A1 = A0 + (size_t)16 * NF;
    const unsigned short* B0 = WeT + (size_t)(nw + li) * NF + q * 8;
    const unsigned short* B1 = B0 + (size_t)16 * NF;

    f32x4 acc[2][2] = {};
#pragma unroll 2
    for (int k0 = 0; k0 < NF; k0 += 32) {
        float4 a0l = *(const float4*)(A0 + k0);
        float4 a0h = *(const float4*)(A0 + k0 + 4);
        float4 a1l = *(const float4*)(A1 + k0);
        float4 a1h = *(const float4*)(A1 + k0 + 4);
        us8 bv0 = *(const us8*)(B0 + k0);
        us8 bv1 = *(const us8*)(B1 + k0);
        uint4 p0, p1;
        p0.x = cvt2(a0l.x, a0l.y); p0.y = cvt2(a0l.z, a0l.w);
        p0.z = cvt2(a0h.x, a0h.y); p0.w = cvt2(a0h.z, a0h.w);
        p1.x = cvt2(a1l.x, a1l.y); p1.y = cvt2(a1l.z, a1l.w);
        p1.z = cvt2(a1h.x, a1h.y); p1.w = cvt2(a1h.z, a1h.w);
        bf16x8 af0 = __builtin_bit_cast(bf16x8, p0);
        bf16x8 af1 = __builtin_bit_cast(bf16x8, p1);
        bf16x8 bf0 = __builtin_bit_cast(bf16x8, bv0);
        bf16x8 bf1 = __builtin_bit_cast(bf16x8, bv1);
        acc[0][0] = __builtin_amdgcn_mfma_f32_16x16x32_bf16(bf0, af0, acc[0][0], 0, 0, 0);
        acc[0][1] = __builtin_amdgcn_mfma_f32_16x16x32_bf16(bf1, af0, acc[0][1], 0, 0, 0);
        acc[1][0] = __builtin_amdgcn_mfma_f32_16x16x32_bf16(bf0, af1, acc[1][0], 0, 0, 0);
        acc[1][1] = __builtin_amdgcn_mfma_f32_16x16x32_bf16(bf1, af1, acc[1][1], 0, 0, 0);
    }

    // epilogue: g -> swizzled LDS + fused critic
#pragma unroll
    for (int i = 0; i < 2; i++) {
        float csum = 0.f;
        const int m = i * 16 + li;
#pragma unroll
        for (int j = 0; j < 2; j++) {
            int colb = nw + j * 16 + q * 4;
            float4 be4 = *(const float4*)&be[colb];
            float4 wc4 = *(const float4*)&Wc[colb];
            float v0 = acc[i][j][0] + be4.x;
            float v1 = acc[i][j][1] + be4.y;
            float v2 = acc[i][j][2] + be4.z;
            float v3 = acc[i][j][3] + be4.w;
            csum += v0 * wc4.x + v1 * wc4.y + v2 * wc4.z + v3 * wc4.w;
            ushort4 st = { f2bf(v0), f2bf(v1), f2bf(v2), f2bf(v3) };
            int sl = (colb >> 3) ^ m;
            *(ushort4*)&gs[m * 256 + sl * 8 + (q & 1) * 4] = st;
        }
        csum += __shfl_down(csum, 32);
        csum += __shfl_down(csum, 16);
        if (lane < 16) credu[w][i * 16 + lane] = csum;
    }
    __syncthreads();   // the ONE barrier: gs + credu ready
    if (t < 32) {
        float cs = 0.f;
#pragma unroll
        for (int ww = 0; ww < 8; ww++) cs += credu[ww][t];
        cpart[m0 + t] = cs;
    }

    // ---------------- phase 2: g @ Wd + MSE (K=256, no barriers) ----------------
    float lsum = 0.f;
    const int nbw = w * 128;   // wave owns 128 of F=1024, in 2 passes of 64
#pragma unroll
    for (int pass = 0; pass < 2; ++pass) {
        const int nbase = nbw + pass * 64;
        const unsigned short* W0 = WdT + (size_t)(nbase + li) * NH + q * 8;
        const unsigned short* W1 = W0 + (size_t)16 * NH;
        const unsigned short* W2 = W0 + (size_t)32 * NH;
        const unsigned short* W3 = W0 + (size_t)48 * NH;
        f32x4 a2[2][4] = {};
#pragma unroll 4
        for (int kc = 0; kc < 8; ++kc) {
            bf16x8 af[2];
#pragma unroll
            for (int i = 0; i < 2; i++) {
                int m = i * 16 + li;
                int sl = (kc * 4 + q) ^ m;
                af[i] = __builtin_bit_cast(bf16x8, *(const us8*)&gs[m * 256 + sl * 8]);
            }
            bf16x8 b0 = __builtin_bit_cast(bf16x8, *(const us8*)(W0 + kc * 32));
            bf16x8 b1 = __builtin_bit_cast(bf16x8, *(const us8*)(W1 + kc * 32));
            bf16x8 b2 = __builtin_bit_cast(bf16x8, *(const us8*)(W2 + kc * 32));
            bf16x8 b3 = __builtin_bit_cast(bf16x8, *(const us8*)(W3 + kc * 32));
#pragma unroll
            for (int i = 0; i < 2; i++) {
                a2[i][0] = __builtin_amdgcn_mfma_f32_16x16x32_bf16(b0, af[i], a2[i][0], 0, 0, 0);
                a2[i][1] = __builtin_amdgcn_mfma_f32_16x16x32_bf16(b1, af[i], a2[i][1], 0, 0, 0);
                a2[i][2] = __builtin_amdgcn_mfma_f32_16x16x32_bf16(b2, af[i], a2[i][2], 0, 0, 0);
                a2[i][3] = __builtin_amdgcn_mfma_f32_16x16x32_bf16(b3, af[i], a2[i][3], 0, 0, 0);
            }
        }
        // per-pass epilogue: rec vs X (X re-read served by L3)
#pragma unroll
        for (int i = 0; i < 2; i++) {
            const size_t rowoff = (size_t)(m0 + i * 16 + li) * NF;
#pragma unroll
            for (int j = 0; j < 4; j++) {
                int colb = nbase + j * 16 + q * 4;
                float4 bd4 = *(const float4*)&bd[colb];
                float4 xr  = *(const float4*)&X[rowoff + colb];
                float d0 = a2[i][j][0] + bd4.x - xr.x;
                float d1 = a2[i][j][1] + bd4.y - xr.y;
                float d2 = a2[i][j][2] + bd4.z - xr.z;
                float d3 = a2[i][j][3] + bd4.w - xr.w;
                lsum += d0 * d0 + d1 * d1 + d2 * d2 + d3 * d3;
            }
        }
    }
#pragma unroll
    for (int o = 32; o; o >>= 1) lsum += __shfl_down(lsum, o);
    if (lane == 0) msred[w] = lsum;
    __syncthreads();
    if (t == 0) {
        float mm = 0.f;
#pragma unroll
        for (int ww = 0; ww < 8; ww++) mm += msred[ww];
        atomicAdd(&hdr[blockIdx.x & 63], mm);
    }
}

// ---------------------------------------------------------------------------
// masked pairwise L1 (no compaction) + fused finalize (last-ticket block).
// grid (16 j-chunks x 32 i-chunks); 3 VALU/pair; ~268M pairs total.
// ---------------------------------------------------------------------------
__global__ __launch_bounds__(256) void pair_fin_kernel(
    const float* __restrict__ c, const int* __restrict__ s, const int* __restrict__ pv,
    float* __restrict__ hdr, float* __restrict__ out) {
    __shared__ float sj[1024];
    __shared__ float mj[1024];
    __shared__ float red[256];
    __shared__ int win;
    const int p = pv[0];
    const int jb = blockIdx.x * 1024;
    for (int j = threadIdx.x; j < 1024; j += 256) {
        int jj = jb + j;
        sj[j] = c[jj];
        mj[j] = (s[jj] != p) ? 1.f : 0.f;
    }
    __syncthreads();
    const int a0 = blockIdx.y * 512 + threadIdx.x, a1 = a0 + 256;
    const float ca0 = c[a0], ca1 = c[a1];
    const float f0 = (s[a0] == p) ? 1.f : 0.f;
    const float f1 = (s[a1] == p) ? 1.f : 0.f;
    float s0 = 0.f, s1 = 0.f;
#pragma unroll 8
    for (int j4 = 0; j4 < 256; j4++) {
        float4 v  = *(const float4*)&sj[j4 * 4];
        float4 m4 = *(const float4*)&mj[j4 * 4];
        s0 = fmaf(m4.x, fabsf(ca0 - v.x), s0);
        s0 = fmaf(m4.y, fabsf(ca0 - v.y), s0);
        s0 = fmaf(m4.z, fabsf(ca0 - v.z), s0);
        s0 = fmaf(m4.w, fabsf(ca0 - v.w), s0);
        s1 = fmaf(m4.x, fabsf(ca1 - v.x), s1);
        s1 = fmaf(m4.y, fabsf(ca1 - v.y), s1);
        s1 = fmaf(m4.z, fabsf(ca1 - v.z), s1);
        s1 = fmaf(m4.w, fabsf(ca1 - v.w), s1);
    }
    float sum = s0 * f0 + s1 * f1;
#pragma unroll
    for (int o = 32; o; o >>= 1) sum += __shfl_down(sum, o);
    if ((threadIdx.x & 63) == 0)
        atomicAdd(&hdr[64 + ((blockIdx.y * 16 + blockIdx.x) & 63)], sum);
    __threadfence();
    __syncthreads();
    if (threadIdx.x == 0)
        win = (atomicAdd((int*)(hdr + 128), 1) == 16 * 32 - 1) ? 1 : 0;
    __syncthreads();
    if (win) {
        // parallel device-scope reads of the 128 partial cells
        float v = (threadIdx.x < 128) ? atomicAdd(&hdr[threadIdx.x], 0.f) : 0.f;
        red[threadIdx.x] = v;
        __syncthreads();
        if (threadIdx.x == 0) {
            float ms = 0.f, ps = 0.f;
            for (int i = 0; i < 64; i++) { ms += red[i]; ps += red[64 + i]; }
            int np = atomicAdd((int*)(hdr + 129), 0);
            out[0] = ms / (float)((size_t)NR * NF);
            out[1] = (float)NR;
            out[2] = ps / (float)np;
            out[3] = (float)np;
        }
    }
}

extern "C" void kernel_launch(void* const* d_in, const int* in_sizes, int n_in,
                              void* d_out, int out_size, void* d_ws, size_t ws_size,
                              hipStream_t stream) {
    const float* X  = (const float*)d_in[0];
    const float* We = (const float*)d_in[1];
    const float* be = (const float*)d_in[2];
    const float* Wd = (const float*)d_in[3];
    const float* bd = (const float*)d_in[4];
    const float* Wc = (const float*)d_in[5];
    // bc (d_in[6]) omitted: cancels in |c_i - c_j|
    const int*   s  = (const int*)d_in[7];
    const int*   pv = (const int*)d_in[8];

    char* ws = (char*)d_ws;
    float* hdr   = (float*)ws;                       // 160 floats (zeroed by prep)
    float* cpart = (float*)(ws + 1024);              // 16384 f, critic scores (bias-free)
    unsigned short* WeT = (unsigned short*)(ws + 1024 + 65536);  // [256][1024] bf16
    unsigned short* WdT = WeT + (size_t)NH * NF;                 // [1024][256] bf16

    prep_kernel<<<512, 256, 0, stream>>>(We, Wd, WeT, WdT, hdr);
    fused_kernel<<<512, 512, 0, stream>>>(X, WeT, WdT, be, bd, Wc, s, pv, cpart, hdr);
    pair_fin_kernel<<<dim3(16, 32), 256, 0, stream>>>(cpart, s, pv, hdr, (float*)d_out);
}

// Round 7
// 219.370 us; speedup vs baseline: 1.2468x; 1.2468x over previous
//
#include <hip/hip_runtime.h>
#include <hip/hip_bf16.h>
#include <cstdint>

// Problem constants (reference: N=16384, F=1024, H=256)
#define NR 16384
#define NF 1024
#define NH 256

typedef __bf16 bf16x8 __attribute__((ext_vector_type(8)));
typedef float f32x4 __attribute__((ext_vector_type(4)));
typedef unsigned short us8 __attribute__((ext_vector_type(8)));

static __device__ __forceinline__ unsigned short f2bf(float f) {
    unsigned u = __float_as_uint(f);
    u += 0x7FFFu + ((u >> 16) & 1u);   // RNE
    return (unsigned short)(u >> 16);
}

// Fragment-major packed layouts (1 KB per cell = 64 lanes x 16 B):
//   Xpk [mb=1024][kc=32][lane=q*16+m][e=8]  = bf16(X[mb*16+m][kc*32+q*8+e])
//   Wepk[nb=  16][kc=32][lane=q*16+n][e=8]  = bf16(We[kc*32+q*8+e][nb*16+n])
//   Wdpk[nb=  64][kc= 8][lane=q*16+n][e=8]  = bf16(Wd[kc*32+q*8+e][nb*16+n])
// A wave's MFMA fragment load == one contiguous, coalesced 1-KB global load.

// ---------------------------------------------------------------------------
// prep: zero hdr + build Xpk / Wepk / Wdpk. grid 1056 x 256 thr.
// ---------------------------------------------------------------------------
__global__ __launch_bounds__(256) void prep_kernel(
    const float* __restrict__ X, const float* __restrict__ We,
    const float* __restrict__ Wd,
    unsigned short* __restrict__ Xpk, unsigned short* __restrict__ Wepk,
    unsigned short* __restrict__ Wdpk, float* __restrict__ hdr) {
    const int b = blockIdx.x, t = threadIdx.x;
    if (b == 0 && t < 160) hdr[t] = 0.f;
    if (b < 1024) {
        // X pack: 16 rows x 1024 k per block
        const int m = t & 15, k8 = t >> 4;
#pragma unroll
        for (int p = 0; p < 8; p++) {
            const int kk = k8 + 16 * p;              // k-octet 0..127
            const float4* xp = (const float4*)(X + (size_t)(b * 16 + m) * NF + kk * 8);
            float4 lo = xp[0], hi = xp[1];
            us8 v;
            v[0] = f2bf(lo.x); v[1] = f2bf(lo.y); v[2] = f2bf(lo.z); v[3] = f2bf(lo.w);
            v[4] = f2bf(hi.x); v[5] = f2bf(hi.y); v[6] = f2bf(hi.z); v[7] = f2bf(hi.w);
            const int kc = kk >> 2, q = kk & 3, lane = q * 16 + m;
            *(us8*)&Xpk[((size_t)(b * 32 + kc)) * 512 + lane * 8] = v;
        }
    } else if (b < 1040) {
        const int nb = b - 1024;                     // 0..15
        const int lane = t & 63, q = lane >> 4, li = lane & 15, idx = t >> 6;
#pragma unroll
        for (int p = 0; p < 8; p++) {
            const int kc = idx + 4 * p;              // 0..31
            us8 v;
#pragma unroll
            for (int e = 0; e < 8; e++)
                v[e] = f2bf(We[(size_t)(kc * 32 + q * 8 + e) * NH + nb * 16 + li]);
            *(us8*)&Wepk[((size_t)(nb * 32 + kc)) * 512 + lane * 8] = v;
        }
    } else {
        const int nb4 = b - 1040;                    // 0..15
        const int lane = t & 63, q = lane >> 4, li = lane & 15, idx = t >> 6;
#pragma unroll
        for (int p = 0; p < 8; p++) {
            const int c = nb4 * 32 + idx + 4 * p;    // 0..511
            const int nb = c >> 3, kc = c & 7;
            us8 v;
#pragma unroll
            for (int e = 0; e < 8; e++)
                v[e] = f2bf(Wd[(size_t)(kc * 32 + q * 8 + e) * NF + nb * 16 + li]);
            *(us8*)&Wdpk[((size_t)(nb * 8 + kc)) * 512 + lane * 8] = v;
        }
    }
}

// ---------------------------------------------------------------------------
// FUSED: grid 256 x 512 thr (8 waves). Block owns 64 m-rows.
//  phase 1: g = X @ We + be (K=1024; A/B fragments = coalesced 1-KB packed
//           loads, no LDS, no barriers). Critic fused. g -> swizzled LDS.
//  phase 2: rec = g @ Wd + bd (K=256; A from LDS, B packed); MSE vs X.
// hdr: [0..63] mse cells, [64..127] pair cells, [128] ticket, [129] nP
// ---------------------------------------------------------------------------
__global__ __launch_bounds__(512) void fused_kernel(
    const float* __restrict__ X, const unsigned short* __restrict__ Xpk,
    const unsigned short* __restrict__ Wepk, const unsigned short* __restrict__ Wdpk,
    const float* __restrict__ be, const float* __restrict__ bd,
    const float* __restrict__ Wc, const int* __restrict__ s, const int* __restrict__ pv,
    float* __restrict__ cpart, float* __restrict__ hdr) {
    __shared__ unsigned short gs[64 * 256];   // 32 KB, slot^row swizzle
    __shared__ float credu[8][32];
    __shared__ float msred[8];
    const int t = threadIdx.x;
    const int mb = blockIdx.x, m0 = mb * 64;
    const int w = t >> 6, lane = t & 63, q = lane >> 4, li = lane & 15;
    const int wmh = w >> 2, wm = wmh * 32;    // m-half: rows [wm, wm+32)
    const int wnq = w & 3, wn = wnq * 64;     // n-quarter (phase 1): [wn, wn+64)

    if (w == 0) {   // protected-row count: one ballot, one atomic per block
        unsigned long long mbal = __ballot(s[m0 + lane] == pv[0]);
        if (lane == 0) atomicAdd((int*)(hdr + 129), (int)__popcll(mbal));
    }

    // ---------------- phase 1: X @ We (no barriers) ----------------
    const unsigned short* Ap0 = Xpk + ((size_t)(mb * 4 + wmh * 2) * 32) * 512 + lane * 8;
    const unsigned short* Ap1 = Ap0 + (size_t)32 * 512;
    const unsigned short* Bp[4];
#pragma unroll
    for (int j = 0; j < 4; j++)
        Bp[j] = Wepk + ((size_t)(wnq * 4 + j) * 32) * 512 + lane * 8;

    f32x4 acc[2][4] = {};
#pragma unroll 2
    for (int kc = 0; kc < 32; ++kc) {
        bf16x8 af0 = __builtin_bit_cast(bf16x8, *(const us8*)(Ap0 + kc * 512));
        bf16x8 af1 = __builtin_bit_cast(bf16x8, *(const us8*)(Ap1 + kc * 512));
        bf16x8 bf[4];
#pragma unroll
        for (int j = 0; j < 4; j++)
            bf[j] = __builtin_bit_cast(bf16x8, *(const us8*)(Bp[j] + kc * 512));
#pragma unroll
        for (int j = 0; j < 4; j++) {
            acc[0][j] = __builtin_amdgcn_mfma_f32_16x16x32_bf16(bf[j], af0, acc[0][j], 0, 0, 0);
            acc[1][j] = __builtin_amdgcn_mfma_f32_16x16x32_bf16(bf[j], af1, acc[1][j], 0, 0, 0);
        }
    }

    // epilogue: g -> swizzled LDS + fused critic (no atomics)
#pragma unroll
    for (int i = 0; i < 2; i++) {
        float csum = 0.f;
        const int ml = wm + i * 16 + li;          // local row 0..63
#pragma unroll
        for (int j = 0; j < 4; j++) {
            const int colb = wn + j * 16 + q * 4;
            float4 be4 = *(const float4*)&be[colb];
            float4 wc4 = *(const float4*)&Wc[colb];
            float v0 = acc[i][j][0] + be4.x;
            float v1 = acc[i][j][1] + be4.y;
            float v2 = acc[i][j][2] + be4.z;
            float v3 = acc[i][j][3] + be4.w;
            csum += v0 * wc4.x + v1 * wc4.y + v2 * wc4.z + v3 * wc4.w;
            ushort4 st = { f2bf(v0), f2bf(v1), f2bf(v2), f2bf(v3) };
            const int sl = (((wn + j * 16) >> 3) + (q >> 1)) ^ (ml & 31);
            *(ushort4*)&gs[ml * 256 + sl * 8 + (q & 1) * 4] = st;
        }
        csum += __shfl_down(csum, 32);
        csum += __shfl_down(csum, 16);
        if (lane < 16) credu[w][i * 16 + lane] = csum;
    }
    __syncthreads();   // gs + credu ready
    if (t < 64) {
        const int half = t >> 5, r = t & 31;
        cpart[m0 + t] = credu[half * 4 + 0][r] + credu[half * 4 + 1][r] +
                        credu[half * 4 + 2][r] + credu[half * 4 + 3][r];
    }

    // ---------------- phase 2: g @ Wd + MSE (no barriers) ----------------
    float lsum = 0.f;
#pragma unroll
    for (int pass = 0; pass < 4; ++pass) {
        const int nbase = pass * 256 + wn;        // wave n-tile [nbase, nbase+64)
        const unsigned short* Wp[4];
#pragma unroll
        for (int j = 0; j < 4; j++)
            Wp[j] = Wdpk + ((size_t)((pass * 16 + wnq * 4 + j) * 8)) * 512 + lane * 8;
        f32x4 a2[2][4] = {};
#pragma unroll
        for (int kc = 0; kc < 8; ++kc) {
            bf16x8 af[2];
#pragma unroll
            for (int i = 0; i < 2; i++) {
                const int ml = wm + i * 16 + li;
                const int sp = (kc * 4 + q) ^ (ml & 31);
                af[i] = __builtin_bit_cast(bf16x8, *(const us8*)&gs[ml * 256 + sp * 8]);
            }
#pragma unroll
            for (int j = 0; j < 4; j++) {
                bf16x8 bf = __builtin_bit_cast(bf16x8, *(const us8*)(Wp[j] + kc * 512));
                a2[0][j] = __builtin_amdgcn_mfma_f32_16x16x32_bf16(bf, af[0], a2[0][j], 0, 0, 0);
                a2[1][j] = __builtin_amdgcn_mfma_f32_16x16x32_bf16(bf, af[1], a2[1][j], 0, 0, 0);
            }
        }
#pragma unroll
        for (int i = 0; i < 2; i++) {
            const size_t rowoff = (size_t)(m0 + wm + i * 16 + li) * NF;
#pragma unroll
            for (int j = 0; j < 4; j++) {
                const int colb = nbase + j * 16 + q * 4;
                float4 bd4 = *(const float4*)&bd[colb];
                float4 xr  = *(const float4*)&X[rowoff + colb];
                float d0 = a2[i][j][0] + bd4.x - xr.x;
                float d1 = a2[i][j][1] + bd4.y - xr.y;
                float d2 = a2[i][j][2] + bd4.z - xr.z;
                float d3 = a2[i][j][3] + bd4.w - xr.w;
                lsum += d0 * d0 + d1 * d1 + d2 * d2 + d3 * d3;
            }
        }
    }
#pragma unroll
    for (int o = 32; o; o >>= 1) lsum += __shfl_down(lsum, o);
    if (lane == 0) msred[w] = lsum;
    __syncthreads();
    if (t == 0) {
        float mm = 0.f;
#pragma unroll
        for (int ww = 0; ww < 8; ww++) mm += msred[ww];
        atomicAdd(&hdr[mb & 63], mm);
    }
}

// ---------------------------------------------------------------------------
// masked pairwise L1 + fused finalize (last-ticket block writes d_out)
// ---------------------------------------------------------------------------
__global__ __launch_bounds__(256) void pair_fin_kernel(
    const float* __restrict__ c, const int* __restrict__ s, const int* __restrict__ pv,
    float* __restrict__ hdr, float* __restrict__ out) {
    __shared__ float sj[1024];
    __shared__ float mj[1024];
    __shared__ float red[256];
    __shared__ int win;
    const int p = pv[0];
    const int jb = blockIdx.x * 1024;
    for (int j = threadIdx.x; j < 1024; j += 256) {
        int jj = jb + j;
        sj[j] = c[jj];
        mj[j] = (s[jj] != p) ? 1.f : 0.f;
    }
    __syncthreads();
    const int a0 = blockIdx.y * 512 + threadIdx.x, a1 = a0 + 256;
    const float ca0 = c[a0], ca1 = c[a1];
    const float f0 = (s[a0] == p) ? 1.f : 0.f;
    const float f1 = (s[a1] == p) ? 1.f : 0.f;
    float s0 = 0.f, s1 = 0.f;
#pragma unroll 8
    for (int j4 = 0; j4 < 256; j4++) {
        float4 v  = *(const float4*)&sj[j4 * 4];
        float4 m4 = *(const float4*)&mj[j4 * 4];
        s0 = fmaf(m4.x, fabsf(ca0 - v.x), s0);
        s0 = fmaf(m4.y, fabsf(ca0 - v.y), s0);
        s0 = fmaf(m4.z, fabsf(ca0 - v.z), s0);
        s0 = fmaf(m4.w, fabsf(ca0 - v.w), s0);
        s1 = fmaf(m4.x, fabsf(ca1 - v.x), s1);
        s1 = fmaf(m4.y, fabsf(ca1 - v.y), s1);
        s1 = fmaf(m4.z, fabsf(ca1 - v.z), s1);
        s1 = fmaf(m4.w, fabsf(ca1 - v.w), s1);
    }
    float sum = s0 * f0 + s1 * f1;
#pragma unroll
    for (int o = 32; o; o >>= 1) sum += __shfl_down(sum, o);
    if ((threadIdx.x & 63) == 0)
        atomicAdd(&hdr[64 + ((blockIdx.y * 16 + blockIdx.x) & 63)], sum);
    __threadfence();
    __syncthreads();
    if (threadIdx.x == 0)
        win = (atomicAdd((int*)(hdr + 128), 1) == 16 * 32 - 1) ? 1 : 0;
    __syncthreads();
    if (win) {
        float v = (threadIdx.x < 128) ? atomicAdd(&hdr[threadIdx.x], 0.f) : 0.f;
        red[threadIdx.x] = v;
        __syncthreads();
        if (threadIdx.x == 0) {
            float ms = 0.f, ps = 0.f;
            for (int i = 0; i < 64; i++) { ms += red[i]; ps += red[64 + i]; }
            int np = atomicAdd((int*)(hdr + 129), 0);
            out[0] = ms / (float)((size_t)NR * NF);
            out[1] = (float)NR;
            out[2] = ps / (float)np;
            out[3] = (float)np;
        }
    }
}

extern "C" void kernel_launch(void* const* d_in, const int* in_sizes, int n_in,
                              void* d_out, int out_size, void* d_ws, size_t ws_size,
                              hipStream_t stream) {
    const float* X  = (const float*)d_in[0];
    const float* We = (const float*)d_in[1];
    const float* be = (const float*)d_in[2];
    const float* Wd = (const float*)d_in[3];
    const float* bd = (const float*)d_in[4];
    const float* Wc = (const float*)d_in[5];
    // bc (d_in[6]) omitted: cancels in |c_i - c_j|
    const int*   s  = (const int*)d_in[7];
    const int*   pv = (const int*)d_in[8];

    char* ws = (char*)d_ws;
    float* hdr   = (float*)ws;                                   // 160 f
    float* cpart = (float*)(ws + 1024);                          // 16384 f
    unsigned short* Xpk  = (unsigned short*)(ws + 1024 + 65536); // 32 MB
    unsigned short* Wepk = Xpk + (size_t)NR * NF;                // 512 KB
    unsigned short* Wdpk = Wepk + (size_t)NH * NF;               // 512 KB

    prep_kernel<<<1056, 256, 0, stream>>>(X, We, Wd, Xpk, Wepk, Wdpk, hdr);
    fused_kernel<<<256, 512, 0, stream>>>(X, Xpk, Wepk, Wdpk, be, bd, Wc, s, pv, cpart, hdr);
    pair_fin_kernel<<<dim3(16, 32), 256, 0, stream>>>(cpart, s, pv, hdr, (float*)d_out);
}

// Round 8
// 198.039 us; speedup vs baseline: 1.3811x; 1.1077x over previous
//
#include <hip/hip_runtime.h>
#include <hip/hip_bf16.h>
#include <cstdint>

// Problem constants (reference: N=16384, F=1024, H=256)
#define NR 16384
#define NF 1024
#define NH 256

typedef __bf16 bf16x8 __attribute__((ext_vector_type(8)));
typedef float f32x4 __attribute__((ext_vector_type(4)));
typedef unsigned short us8 __attribute__((ext_vector_type(8)));

static __device__ __forceinline__ unsigned short f2bf(float f) {
    unsigned u = __float_as_uint(f);
    u += 0x7FFFu + ((u >> 16) & 1u);   // RNE
    return (unsigned short)(u >> 16);
}
static __device__ __forceinline__ float bf2f(unsigned short h) {
    return __uint_as_float(((unsigned)h) << 16);
}

// Fragment-major packed layouts (1 KB per cell = 64 lanes x 16 B):
//   Xpk [mb=1024][kc=32][lane=q*16+m][e=8]  = bf16(X[mb*16+m][kc*32+q*8+e])
//   Wepk[nb=  16][kc=32][lane=q*16+n][e=8]  = bf16(We[kc*32+q*8+e][nb*16+n])
//   Wdpk[nb=  64][kc= 8][lane=q*16+n][e=8]  = bf16(Wd[kc*32+q*8+e][nb*16+n])
// hdr: [0..63] mse cells, [64..127] pair cells, [128] ticket, [129] nP, [130] nR

// ---------------------------------------------------------------------------
// prep: zero hdr + build Xpk (LDS-staged, coalesced both sides) / Wepk / Wdpk
// grid 1056 x 256 thr: b<1024 X-pack (16 rows), 1024..1039 We, 1040..1055 Wd
// ---------------------------------------------------------------------------
__global__ __launch_bounds__(256) void prep_kernel(
    const float* __restrict__ X, const float* __restrict__ We,
    const float* __restrict__ Wd,
    unsigned short* __restrict__ Xpk, unsigned short* __restrict__ Wepk,
    unsigned short* __restrict__ Wdpk, float* __restrict__ hdr) {
    const int b = blockIdx.x, t = threadIdx.x;
    if (b == 0 && t < 192) hdr[t] = 0.f;
    if (b < 1024) {
        __shared__ float tile[16 * 272];
        const int r0 = b * 16;
#pragma unroll
        for (int ch = 0; ch < 4; ++ch) {
            const int c0 = ch * 256;
#pragma unroll
            for (int p = 0; p < 4; ++p) {
                int idx = t + 256 * p;                   // 0..1023
                int r = idx >> 6, c4 = idx & 63;
                *(float4*)&tile[r * 272 + c4 * 4] =
                    *(const float4*)(X + (size_t)(r0 + r) * NF + c0 + c4 * 4);
            }
            __syncthreads();
#pragma unroll
            for (int p = 0; p < 2; ++p) {
                int u = t + 256 * p;                     // 0..511
                int cell = u >> 6, lane = u & 63;
                int m = lane & 15, q = lane >> 4;
                const float* src = &tile[m * 272 + cell * 32 + q * 8];
                us8 v;
#pragma unroll
                for (int e = 0; e < 8; e++) v[e] = f2bf(src[e]);
                *(us8*)&Xpk[((size_t)(b * 32 + ch * 8 + cell)) * 512 + lane * 8] = v;
            }
            __syncthreads();
        }
    } else if (b < 1040) {
        const int nb = b - 1024;
        const int lane = t & 63, q = lane >> 4, li = lane & 15, idx = t >> 6;
#pragma unroll
        for (int p = 0; p < 8; p++) {
            const int kc = idx + 4 * p;                  // 0..31
            us8 v;
#pragma unroll
            for (int e = 0; e < 8; e++)
                v[e] = f2bf(We[(size_t)(kc * 32 + q * 8 + e) * NH + nb * 16 + li]);
            *(us8*)&Wepk[((size_t)(nb * 32 + kc)) * 512 + lane * 8] = v;
        }
    } else {
        const int nb4 = b - 1040;
        const int lane = t & 63, q = lane >> 4, li = lane & 15, idx = t >> 6;
#pragma unroll
        for (int p = 0; p < 8; p++) {
            const int c = nb4 * 32 + idx + 4 * p;        // 0..511
            const int nb = c >> 3, kc = c & 7;
            us8 v;
#pragma unroll
            for (int e = 0; e < 8; e++)
                v[e] = f2bf(Wd[(size_t)(kc * 32 + q * 8 + e) * NF + nb * 16 + li]);
            *(us8*)&Wdpk[((size_t)(nb * 8 + kc)) * 512 + lane * 8] = v;
        }
    }
}

// ---------------------------------------------------------------------------
// FUSED: grid 512 x 256 thr (4 waves), 32 m-rows/block (2 blocks/CU).
//  phase 1: g = X @ We + be (K=1024, 2-deep register prefetch, no LDS/barriers)
//  phase 2: rec = g @ Wd + bd; MSE vs bf16 X from Xpk. Critic fused.
// ---------------------------------------------------------------------------
__global__ __launch_bounds__(256) void fused_kernel(
    const unsigned short* __restrict__ Xpk,
    const unsigned short* __restrict__ Wepk, const unsigned short* __restrict__ Wdpk,
    const float* __restrict__ be, const float* __restrict__ bd,
    const float* __restrict__ Wc,
    float* __restrict__ cpart, float* __restrict__ hdr) {
    __shared__ unsigned short gs[32 * 256];   // 16 KB, granule^row swizzle
    __shared__ float credu[4][32];
    __shared__ float msred[4];
    const int t = threadIdx.x;
    const int b = blockIdx.x, m0 = b * 32;
    const int w = t >> 6, lane = t & 63, q = lane >> 4, li = lane & 15;
    const int wn = w * 64;    // phase-1 wave n-slice [wn, wn+64)

    // ---------------- phase 1: X @ We (no barriers, 2-deep prefetch) --------
    const unsigned short* Ap0 = Xpk + ((size_t)(b * 2) * 32) * 512 + lane * 8;
    const unsigned short* Ap1 = Ap0 + (size_t)32 * 512;
    const unsigned short* Bp[4];
#pragma unroll
    for (int j = 0; j < 4; j++)
        Bp[j] = Wepk + ((size_t)(w * 4 + j) * 32) * 512 + lane * 8;

    us8 fa[2][2], fb[2][4];
#pragma unroll
    for (int z = 0; z < 2; ++z) {
        fa[z][0] = *(const us8*)(Ap0 + z * 512);
        fa[z][1] = *(const us8*)(Ap1 + z * 512);
#pragma unroll
        for (int j = 0; j < 4; j++) fb[z][j] = *(const us8*)(Bp[j] + z * 512);
    }
    f32x4 acc[2][4] = {};
#pragma unroll
    for (int kc = 0; kc < 32; ++kc) {
        const int cb = kc & 1;
        us8 na0, na1, nbv[4];
        const bool pf = (kc + 2 < 32);
        if (pf) {
            na0 = *(const us8*)(Ap0 + (kc + 2) * 512);
            na1 = *(const us8*)(Ap1 + (kc + 2) * 512);
#pragma unroll
            for (int j = 0; j < 4; j++) nbv[j] = *(const us8*)(Bp[j] + (kc + 2) * 512);
        }
        bf16x8 a0 = __builtin_bit_cast(bf16x8, fa[cb][0]);
        bf16x8 a1 = __builtin_bit_cast(bf16x8, fa[cb][1]);
#pragma unroll
        for (int j = 0; j < 4; j++) {
            bf16x8 bf = __builtin_bit_cast(bf16x8, fb[cb][j]);
            acc[0][j] = __builtin_amdgcn_mfma_f32_16x16x32_bf16(bf, a0, acc[0][j], 0, 0, 0);
            acc[1][j] = __builtin_amdgcn_mfma_f32_16x16x32_bf16(bf, a1, acc[1][j], 0, 0, 0);
        }
        if (pf) {
            fa[cb][0] = na0; fa[cb][1] = na1;
#pragma unroll
            for (int j = 0; j < 4; j++) fb[cb][j] = nbv[j];
        }
    }

    // epilogue: g -> swizzled LDS + fused critic
#pragma unroll
    for (int i = 0; i < 2; i++) {
        float csum = 0.f;
        const int ml = i * 16 + li;
#pragma unroll
        for (int j = 0; j < 4; j++) {
            const int colb = wn + j * 16 + q * 4;
            float4 be4 = *(const float4*)&be[colb];
            float4 wc4 = *(const float4*)&Wc[colb];
            float v0 = acc[i][j][0] + be4.x;
            float v1 = acc[i][j][1] + be4.y;
            float v2 = acc[i][j][2] + be4.z;
            float v3 = acc[i][j][3] + be4.w;
            csum += v0 * wc4.x + v1 * wc4.y + v2 * wc4.z + v3 * wc4.w;
            ushort4 st = { f2bf(v0), f2bf(v1), f2bf(v2), f2bf(v3) };
            const int phys = ((colb >> 3)) ^ ml;        // granule xor row
            *(ushort4*)&gs[ml * 256 + phys * 8 + (q & 1) * 4] = st;
        }
        csum += __shfl_down(csum, 32);
        csum += __shfl_down(csum, 16);
        if (lane < 16) credu[w][i * 16 + lane] = csum;
    }
    __syncthreads();   // gs + credu ready
    if (t < 32)
        cpart[m0 + t] = credu[0][t] + credu[1][t] + credu[2][t] + credu[3][t];

    // ---------------- phase 2: g @ Wd + MSE (no barriers) -------------------
    const unsigned short* Wp = Wdpk + lane * 8;
    us8 gb[2][4];
#pragma unroll
    for (int z = 0; z < 2; ++z)
#pragma unroll
        for (int j = 0; j < 4; j++)
            gb[z][j] = *(const us8*)(Wp + ((size_t)((w * 4 + j) * 8 + z)) * 512);

    float lsum = 0.f;
    f32x4 a2[2][4] = {};
#pragma unroll
    for (int it = 0; it < 32; ++it) {
        const int cb = it & 1, pass = it >> 3, kc = it & 7;
        us8 nbv[4];
        const bool pf = (it + 2 < 32);
        if (pf) {
            const int p2 = (it + 2) >> 3, k2 = (it + 2) & 7;
#pragma unroll
            for (int j = 0; j < 4; j++)
                nbv[j] = *(const us8*)(Wp + ((size_t)((p2 * 16 + w * 4 + j) * 8 + k2)) * 512);
        }
        bf16x8 af[2];
#pragma unroll
        for (int i = 0; i < 2; i++) {
            const int ml = i * 16 + li;
            const int phys = (kc * 4 + q) ^ ml;
            af[i] = __builtin_bit_cast(bf16x8, *(const us8*)&gs[ml * 256 + phys * 8]);
        }
#pragma unroll
        for (int j = 0; j < 4; j++) {
            bf16x8 bf = __builtin_bit_cast(bf16x8, gb[cb][j]);
            a2[0][j] = __builtin_amdgcn_mfma_f32_16x16x32_bf16(bf, af[0], a2[0][j], 0, 0, 0);
            a2[1][j] = __builtin_amdgcn_mfma_f32_16x16x32_bf16(bf, af[1], a2[1][j], 0, 0, 0);
        }
        if (pf) {
#pragma unroll
            for (int j = 0; j < 4; j++) gb[cb][j] = nbv[j];
        }
        if (kc == 7) {   // per-pass epilogue: rec vs bf16 X (Xpk)
#pragma unroll
            for (int i = 0; i < 2; i++) {
                const int mbp = b * 2 + i;
#pragma unroll
                for (int j = 0; j < 4; j++) {
                    const int colb = pass * 256 + wn + j * 16 + q * 4;
                    float4 bd4 = *(const float4*)&bd[colb];
                    const int kcx = pass * 8 + w * 2 + (j >> 1);
                    const int qp = (j & 1) * 2 + (q >> 1), h = q & 1;
                    ushort4 xv = *(const ushort4*)&Xpk[((size_t)(mbp * 32 + kcx)) * 512 +
                                                       (qp * 16 + li) * 8 + h * 4];
                    float d0 = a2[i][j][0] + bd4.x - bf2f(xv.x);
                    float d1 = a2[i][j][1] + bd4.y - bf2f(xv.y);
                    float d2 = a2[i][j][2] + bd4.z - bf2f(xv.z);
                    float d3 = a2[i][j][3] + bd4.w - bf2f(xv.w);
                    lsum += d0 * d0 + d1 * d1 + d2 * d2 + d3 * d3;
                    a2[i][j] = (f32x4){0.f, 0.f, 0.f, 0.f};
                }
            }
        }
    }
#pragma unroll
    for (int o = 32; o; o >>= 1) lsum += __shfl_down(lsum, o);
    if (lane == 0) msred[w] = lsum;
    __syncthreads();
    if (t == 0)
        atomicAdd(&hdr[b & 63], msred[0] + msred[1] + msred[2] + msred[3]);
}

// ---------------------------------------------------------------------------
// compaction: cP = c[s==p], cR = c[s!=p] (order-free), wave-aggregated atomics
// ---------------------------------------------------------------------------
__global__ __launch_bounds__(256) void compact_kernel(
    const float* __restrict__ c, const int* __restrict__ s, const int* __restrict__ pv,
    float* __restrict__ cP, float* __restrict__ cR, int* __restrict__ cnt) {
    int i = blockIdx.x * 256 + threadIdx.x;
    float ci = c[i];
    bool pr = (s[i] == pv[0]);
    int lane = threadIdx.x & 63;
    unsigned long long m = __ballot(pr);
    {
        int cm = __popcll(m);
        int base = 0;
        if (lane == 0 && cm) base = atomicAdd(&cnt[0], cm);
        base = __shfl(base, 0);
        int off = __popcll(m & ((1ull << lane) - 1ull));
        if (pr) cP[base + off] = ci;
    }
    {
        unsigned long long mm = ~m;
        int cm = __popcll(mm);
        int base = 0;
        if (lane == 0 && cm) base = atomicAdd(&cnt[1], cm);
        base = __shfl(base, 0);
        int off = __popcll(mm & ((1ull << lane) - 1ull));
        if (!pr) cR[base + off] = ci;
    }
}

// ---------------------------------------------------------------------------
// compacted pairwise L1 + fused finalize (last-ticket block writes d_out)
// grid (16 j-chunks x 32 i-chunks of 512)
// ---------------------------------------------------------------------------
__global__ __launch_bounds__(256) void pair_fin_kernel(
    const float* __restrict__ cP, const float* __restrict__ cR,
    float* __restrict__ hdr, float* __restrict__ out) {
    __shared__ float sj[1024];
    __shared__ float red[256];
    __shared__ int win;
    const int nP = ((const int*)hdr)[129];
    const int nR = ((const int*)hdr)[130];
    const int jb = blockIdx.x * 1024;
    int jn = nR - jb; if (jn < 0) jn = 0; if (jn > 1024) jn = 1024;
    float sum = 0.f;
    if (jn > 0 && blockIdx.y * 512 < nP) {
        for (int j = threadIdx.x; j < 1024; j += 256)
            sj[j] = (jb + j < nR) ? cR[jb + j] : 0.f;
        __syncthreads();
        const int a0 = blockIdx.y * 512 + threadIdx.x, a1 = a0 + 256;
        const float ca0 = (a0 < nP) ? cP[a0] : 0.f;
        const float ca1 = (a1 < nP) ? cP[a1] : 0.f;
        float s0 = 0.f, s1 = 0.f;
#pragma unroll 8
        for (int j4 = 0; j4 < 256; j4++) {
            float4 v = *(const float4*)&sj[j4 * 4];
            s0 += fabsf(ca0 - v.x) + fabsf(ca0 - v.y) + fabsf(ca0 - v.z) + fabsf(ca0 - v.w);
            s1 += fabsf(ca1 - v.x) + fabsf(ca1 - v.y) + fabsf(ca1 - v.z) + fabsf(ca1 - v.w);
        }
        float pad = (float)(1024 - jn);
        s0 -= pad * fabsf(ca0);
        s1 -= pad * fabsf(ca1);
        if (a0 >= nP) s0 = 0.f;
        if (a1 >= nP) s1 = 0.f;
        sum = s0 + s1;
#pragma unroll
        for (int o = 32; o; o >>= 1) sum += __shfl_down(sum, o);
        if ((threadIdx.x & 63) == 0 && sum != 0.f)
            atomicAdd(&hdr[64 + ((blockIdx.y * 16 + blockIdx.x) & 63)], sum);
    }
    __threadfence();
    __syncthreads();
    if (threadIdx.x == 0)
        win = (atomicAdd((int*)(hdr + 128), 1) == 16 * 32 - 1) ? 1 : 0;
    __syncthreads();
    if (win) {
        float v = (threadIdx.x < 128) ? atomicAdd(&hdr[threadIdx.x], 0.f) : 0.f;
        red[threadIdx.x] = v;
        __syncthreads();
        if (threadIdx.x == 0) {
            float ms = 0.f, ps = 0.f;
            for (int i = 0; i < 64; i++) { ms += red[i]; ps += red[64 + i]; }
            int np = atomicAdd((int*)(hdr + 129), 0);
            out[0] = ms / (float)((size_t)NR * NF);
            out[1] = (float)NR;
            out[2] = ps / (float)np;
            out[3] = (float)np;
        }
    }
}

extern "C" void kernel_launch(void* const* d_in, const int* in_sizes, int n_in,
                              void* d_out, int out_size, void* d_ws, size_t ws_size,
                              hipStream_t stream) {
    const float* X  = (const float*)d_in[0];
    const float* We = (const float*)d_in[1];
    const float* be = (const float*)d_in[2];
    const float* Wd = (const float*)d_in[3];
    const float* bd = (const float*)d_in[4];
    const float* Wc = (const float*)d_in[5];
    // bc (d_in[6]) omitted: cancels in |c_i - c_j|
    const int*   s  = (const int*)d_in[7];
    const int*   pv = (const int*)d_in[8];

    char* ws = (char*)d_ws;
    float* hdr   = (float*)ws;                                    // 192 f
    float* cpart = (float*)(ws + 1024);                           // 16384 f
    float* cP    = (float*)(ws + 1024 + 65536);
    float* cR    = (float*)(ws + 1024 + 2 * 65536);
    unsigned short* Xpk  = (unsigned short*)(ws + 1024 + 3 * 65536); // 32 MB
    unsigned short* Wepk = Xpk + (size_t)NR * NF;                 // 512 KB
    unsigned short* Wdpk = Wepk + (size_t)NH * NF;                // 512 KB

    prep_kernel<<<1056, 256, 0, stream>>>(X, We, Wd, Xpk, Wepk, Wdpk, hdr);
    fused_kernel<<<512, 256, 0, stream>>>(Xpk, Wepk, Wdpk, be, bd, Wc, cpart, hdr);
    compact_kernel<<<64, 256, 0, stream>>>(cpart, s, pv, cP, cR, (int*)hdr + 129);
    pair_fin_kernel<<<dim3(16, 32), 256, 0, stream>>>(cP, cR, hdr, (float*)d_out);
}

// Round 9
// 191.605 us; speedup vs baseline: 1.4274x; 1.0336x over previous
//
#include <hip/hip_runtime.h>
#include <hip/hip_bf16.h>
#include <cstdint>

// Problem constants (reference: N=16384, F=1024, H=256)
#define NR 16384
#define NF 1024
#define NH 256

typedef __bf16 bf16x8 __attribute__((ext_vector_type(8)));
typedef float f32x4 __attribute__((ext_vector_type(4)));
typedef unsigned short us8 __attribute__((ext_vector_type(8)));

static __device__ __forceinline__ unsigned short f2bf(float f) {
    unsigned u = __float_as_uint(f);
    u += 0x7FFFu + ((u >> 16) & 1u);   // RNE
    return (unsigned short)(u >> 16);
}

// Fragment-major packed weights (1 KB per cell = 64 lanes x 16 B):
//   Wepk[nb=16][kc=32][lane=q*16+n][e=8] = bf16(We[kc*32+q*8+e][nb*16+n])
//   Wdpk[nb=64][kc= 8][lane=q*16+n][e=8] = bf16(Wd[kc*32+q*8+e][nb*16+n])
// hdr: [0..63] mse cells, [64..127] pair cells, [128] pair ticket,
//      [129] nP (int), [130] nR (int)

// ---------------------------------------------------------------------------
// prep: zero hdr + pack weights. 32 blocks: b<16 We, else Wd.
// ---------------------------------------------------------------------------
__global__ __launch_bounds__(256) void prep_kernel(
    const float* __restrict__ We, const float* __restrict__ Wd,
    unsigned short* __restrict__ Wepk, unsigned short* __restrict__ Wdpk,
    float* __restrict__ hdr) {
    const int b = blockIdx.x, t = threadIdx.x;
    if (b == 0 && t < 192) hdr[t] = 0.f;
    const int lane = t & 63, q = lane >> 4, li = lane & 15, idx = t >> 6;
    if (b < 16) {
        const int nb = b;
#pragma unroll
        for (int p = 0; p < 8; p++) {
            const int kc = idx + 4 * p;                  // 0..31
            us8 v;
#pragma unroll
            for (int e = 0; e < 8; e++)
                v[e] = f2bf(We[(size_t)(kc * 32 + q * 8 + e) * NH + nb * 16 + li]);
            *(us8*)&Wepk[((size_t)(nb * 32 + kc)) * 512 + lane * 8] = v;
        }
    } else {
        const int nb4 = b - 16;                          // 0..15
#pragma unroll
        for (int p = 0; p < 8; p++) {
            const int c = nb4 * 32 + idx + 4 * p;        // 0..511
            const int nb = c >> 3, kc = c & 7;
            us8 v;
#pragma unroll
            for (int e = 0; e < 8; e++)
                v[e] = f2bf(Wd[(size_t)(kc * 32 + q * 8 + e) * NF + nb * 16 + li]);
            *(us8*)&Wdpk[((size_t)(nb * 8 + kc)) * 512 + lane * 8] = v;
        }
    }
}

// ---------------------------------------------------------------------------
// FUSED: grid 512 x 256 thr (4 waves), 32 m-rows/block, 64 KB LDS (2 blk/CU).
//  phase 0: stage own X strip (32x1024) -> LDS bf16, granule^row swizzle
//  phase 1: g = X @ We + be (A from LDS, B = Wepk 2-deep prefetch, no barriers)
//  epilogue: critic c per row -> in-block compaction into cP/cR (no cpart!)
//  phase 2: rec = g @ Wd + bd (A = gs LDS, B = Wdpk prefetch); MSE vs X fp32
// ---------------------------------------------------------------------------
__global__ __launch_bounds__(256) void fused_kernel(
    const float* __restrict__ X,
    const unsigned short* __restrict__ Wepk, const unsigned short* __restrict__ Wdpk,
    const float* __restrict__ be, const float* __restrict__ bd,
    const float* __restrict__ Wc, const int* __restrict__ s, const int* __restrict__ pv,
    float* __restrict__ cP, float* __restrict__ cR, float* __restrict__ hdr) {
    __shared__ union {
        unsigned short xa[32 * 1024];   // 64 KB: bf16 X tile (phases 0/1)
        struct {
            unsigned short gs[32 * 256]; // 16 KB: g tile (phase 2)
            float credu[4][32];
            float msred[4];
        } p2;
    } u;
    const int t = threadIdx.x;
    const int b = blockIdx.x, m0 = b * 32;
    const int w = t >> 6, lane = t & 63, q = lane >> 4, li = lane & 15;
    const int wn = w * 64;    // phase-1 wave n-slice [wn, wn+64)

    // ---------------- phase 0: stage X tile into LDS (bf16, swizzled) ------
    {
        const int r = t >> 3, cg = t & 7;     // row 0..31, chunk-group 0..7
        const float* xrow = X + (size_t)(m0 + r) * NF + cg * 128;
#pragma unroll
        for (int ci = 0; ci < 16; ++ci) {
            float4 lo = *(const float4*)(xrow + ci * 8);
            float4 hi = *(const float4*)(xrow + ci * 8 + 4);
            us8 v;
            v[0] = f2bf(lo.x); v[1] = f2bf(lo.y); v[2] = f2bf(lo.z); v[3] = f2bf(lo.w);
            v[4] = f2bf(hi.x); v[5] = f2bf(hi.y); v[6] = f2bf(hi.z); v[7] = f2bf(hi.w);
            const int ch = cg * 16 + ci;      // k-chunk 0..127
            *(us8*)&u.xa[r * 1024 + ((ch ^ r) & 127) * 8] = v;
        }
    }
    __syncthreads();

    // ---------------- phase 1: X @ We (no barriers, 2-deep B prefetch) ------
    const unsigned short* Bp[4];
#pragma unroll
    for (int j = 0; j < 4; j++)
        Bp[j] = Wepk + ((size_t)(w * 4 + j) * 32) * 512 + lane * 8;

    us8 fb[2][4];
#pragma unroll
    for (int z = 0; z < 2; ++z)
#pragma unroll
        for (int j = 0; j < 4; j++) fb[z][j] = *(const us8*)(Bp[j] + z * 512);

    f32x4 acc[2][4] = {};
#pragma unroll
    for (int kc = 0; kc < 32; ++kc) {
        const int cb = kc & 1;
        us8 nbv[4];
        const bool pf = (kc + 2 < 32);
        if (pf) {
#pragma unroll
            for (int j = 0; j < 4; j++) nbv[j] = *(const us8*)(Bp[j] + (kc + 2) * 512);
        }
        // A fragments from swizzled LDS: row r, chunk kc*4+q
        const int ph0 = ((kc * 4 + q) ^ li) & 127;
        const int ph1 = ((kc * 4 + q) ^ (16 + li)) & 127;
        bf16x8 a0 = __builtin_bit_cast(bf16x8, *(const us8*)&u.xa[li * 1024 + ph0 * 8]);
        bf16x8 a1 = __builtin_bit_cast(bf16x8, *(const us8*)&u.xa[(16 + li) * 1024 + ph1 * 8]);
#pragma unroll
        for (int j = 0; j < 4; j++) {
            bf16x8 bf = __builtin_bit_cast(bf16x8, fb[cb][j]);
            acc[0][j] = __builtin_amdgcn_mfma_f32_16x16x32_bf16(bf, a0, acc[0][j], 0, 0, 0);
            acc[1][j] = __builtin_amdgcn_mfma_f32_16x16x32_bf16(bf, a1, acc[1][j], 0, 0, 0);
        }
        if (pf) {
#pragma unroll
            for (int j = 0; j < 4; j++) fb[cb][j] = nbv[j];
        }
    }
    __syncthreads();   // all waves done reading xa; p2 region writable

    // phase-2 B prefetch (global, independent) issued before epilogue
    const unsigned short* Wp = Wdpk + lane * 8;
    us8 gb[2][4];
#pragma unroll
    for (int z = 0; z < 2; ++z)
#pragma unroll
        for (int j = 0; j < 4; j++)
            gb[z][j] = *(const us8*)(Wp + ((size_t)((w * 4 + j) * 8 + z)) * 512);

    // epilogue: g -> swizzled gs + fused critic
#pragma unroll
    for (int i = 0; i < 2; i++) {
        float csum = 0.f;
        const int ml = i * 16 + li;
#pragma unroll
        for (int j = 0; j < 4; j++) {
            const int colb = wn + j * 16 + q * 4;
            float4 be4 = *(const float4*)&be[colb];
            float4 wc4 = *(const float4*)&Wc[colb];
            float v0 = acc[i][j][0] + be4.x;
            float v1 = acc[i][j][1] + be4.y;
            float v2 = acc[i][j][2] + be4.z;
            float v3 = acc[i][j][3] + be4.w;
            csum += v0 * wc4.x + v1 * wc4.y + v2 * wc4.z + v3 * wc4.w;
            ushort4 st = { f2bf(v0), f2bf(v1), f2bf(v2), f2bf(v3) };
            const int phys = (colb >> 3) ^ ml;
            *(ushort4*)&u.p2.gs[ml * 256 + phys * 8 + (q & 1) * 4] = st;
        }
        csum += __shfl_down(csum, 32);
        csum += __shfl_down(csum, 16);
        if (lane < 16) u.p2.credu[w][i * 16 + lane] = csum;
    }
    __syncthreads();   // gs + credu ready

    // in-block compaction of this block's 32 critic values into cP/cR
    if (t < 32) {
        float cs = u.p2.credu[0][t] + u.p2.credu[1][t] +
                   u.p2.credu[2][t] + u.p2.credu[3][t];
        bool pr = (s[m0 + t] == pv[0]);
        unsigned long long mk = __ballot(pr);
        int np = __popcll(mk);
        int baseP = 0, baseR = 0;
        if (t == 0) {
            baseP = atomicAdd((int*)hdr + 129, np);
            baseR = atomicAdd((int*)hdr + 130, 32 - np);
        }
        baseP = __shfl(baseP, 0);
        baseR = __shfl(baseR, 0);
        int offP = __popcll(mk & ((1ull << t) - 1ull));
        int offR = t - offP;
        if (pr) cP[baseP + offP] = cs; else cR[baseR + offR] = cs;
    }

    // ---------------- phase 2: g @ Wd + MSE (no barriers) -------------------
    float lsum = 0.f;
    f32x4 a2[2][4] = {};
#pragma unroll
    for (int it = 0; it < 32; ++it) {
        const int cb = it & 1, pass = it >> 3, kc = it & 7;
        us8 nbv[4];
        const bool pf = (it + 2 < 32);
        if (pf) {
            const int p2i = (it + 2) >> 3, k2 = (it + 2) & 7;
#pragma unroll
            for (int j = 0; j < 4; j++)
                nbv[j] = *(const us8*)(Wp + ((size_t)((p2i * 16 + w * 4 + j) * 8 + k2)) * 512);
        }
        bf16x8 af[2];
#pragma unroll
        for (int i = 0; i < 2; i++) {
            const int ml = i * 16 + li;
            const int phys = (kc * 4 + q) ^ ml;
            af[i] = __builtin_bit_cast(bf16x8, *(const us8*)&u.p2.gs[ml * 256 + phys * 8]);
        }
#pragma unroll
        for (int j = 0; j < 4; j++) {
            bf16x8 bf = __builtin_bit_cast(bf16x8, gb[cb][j]);
            a2[0][j] = __builtin_amdgcn_mfma_f32_16x16x32_bf16(bf, af[0], a2[0][j], 0, 0, 0);
            a2[1][j] = __builtin_amdgcn_mfma_f32_16x16x32_bf16(bf, af[1], a2[1][j], 0, 0, 0);
        }
        if (pf) {
#pragma unroll
            for (int j = 0; j < 4; j++) gb[cb][j] = nbv[j];
        }
        if (kc == 7) {   // per-pass epilogue: rec vs X fp32 (L3-warm)
#pragma unroll
            for (int i = 0; i < 2; i++) {
                const size_t rowoff = (size_t)(m0 + i * 16 + li) * NF;
#pragma unroll
                for (int j = 0; j < 4; j++) {
                    const int colb = pass * 256 + wn + j * 16 + q * 4;
                    float4 bd4 = *(const float4*)&bd[colb];
                    float4 xr  = *(const float4*)&X[rowoff + colb];
                    float d0 = a2[i][j][0] + bd4.x - xr.x;
                    float d1 = a2[i][j][1] + bd4.y - xr.y;
                    float d2 = a2[i][j][2] + bd4.z - xr.z;
                    float d3 = a2[i][j][3] + bd4.w - xr.w;
                    lsum += d0 * d0 + d1 * d1 + d2 * d2 + d3 * d3;
                    a2[i][j] = (f32x4){0.f, 0.f, 0.f, 0.f};
                }
            }
        }
    }
#pragma unroll
    for (int o = 32; o; o >>= 1) lsum += __shfl_down(lsum, o);
    if (lane == 0) u.p2.msred[w] = lsum;
    __syncthreads();
    if (t == 0)
        atomicAdd(&hdr[b & 63], u.p2.msred[0] + u.p2.msred[1] +
                                u.p2.msred[2] + u.p2.msred[3]);
}

// ---------------------------------------------------------------------------
// compacted pairwise L1 + fused finalize (last-ticket block writes d_out)
// grid (16 j-chunks x 32 i-chunks of 512)
// ---------------------------------------------------------------------------
__global__ __launch_bounds__(256) void pair_fin_kernel(
    const float* __restrict__ cP, const float* __restrict__ cR,
    float* __restrict__ hdr, float* __restrict__ out) {
    __shared__ float sj[1024];
    __shared__ float red[256];
    __shared__ int win;
    const int nP = ((const int*)hdr)[129];
    const int nR = ((const int*)hdr)[130];
    const int jb = blockIdx.x * 1024;
    int jn = nR - jb; if (jn < 0) jn = 0; if (jn > 1024) jn = 1024;
    float sum = 0.f;
    if (jn > 0 && blockIdx.y * 512 < nP) {
        for (int j = threadIdx.x; j < 1024; j += 256)
            sj[j] = (jb + j < nR) ? cR[jb + j] : 0.f;
        __syncthreads();
        const int a0 = blockIdx.y * 512 + threadIdx.x, a1 = a0 + 256;
        const float ca0 = (a0 < nP) ? cP[a0] : 0.f;
        const float ca1 = (a1 < nP) ? cP[a1] : 0.f;
        float s0 = 0.f, s1 = 0.f;
#pragma unroll 8
        for (int j4 = 0; j4 < 256; j4++) {
            float4 v = *(const float4*)&sj[j4 * 4];
            s0 += fabsf(ca0 - v.x) + fabsf(ca0 - v.y) + fabsf(ca0 - v.z) + fabsf(ca0 - v.w);
            s1 += fabsf(ca1 - v.x) + fabsf(ca1 - v.y) + fabsf(ca1 - v.z) + fabsf(ca1 - v.w);
        }
        float pad = (float)(1024 - jn);
        s0 -= pad * fabsf(ca0);
        s1 -= pad * fabsf(ca1);
        if (a0 >= nP) s0 = 0.f;
        if (a1 >= nP) s1 = 0.f;
        sum = s0 + s1;
#pragma unroll
        for (int o = 32; o; o >>= 1) sum += __shfl_down(sum, o);
        if ((threadIdx.x & 63) == 0 && sum != 0.f)
            atomicAdd(&hdr[64 + ((blockIdx.y * 16 + blockIdx.x) & 63)], sum);
    }
    __threadfence();
    __syncthreads();
    if (threadIdx.x == 0)
        win = (atomicAdd((int*)(hdr + 128), 1) == 16 * 32 - 1) ? 1 : 0;
    __syncthreads();
    if (win) {
        float v = (threadIdx.x < 128) ? atomicAdd(&hdr[threadIdx.x], 0.f) : 0.f;
        red[threadIdx.x] = v;
        __syncthreads();
        if (threadIdx.x == 0) {
            float ms = 0.f, ps = 0.f;
            for (int i = 0; i < 64; i++) { ms += red[i]; ps += red[64 + i]; }
            int np = atomicAdd((int*)(hdr + 129), 0);
            out[0] = ms / (float)((size_t)NR * NF);
            out[1] = (float)NR;
            out[2] = ps / (float)np;
            out[3] = (float)np;
        }
    }
}

extern "C" void kernel_launch(void* const* d_in, const int* in_sizes, int n_in,
                              void* d_out, int out_size, void* d_ws, size_t ws_size,
                              hipStream_t stream) {
    const float* X  = (const float*)d_in[0];
    const float* We = (const float*)d_in[1];
    const float* be = (const float*)d_in[2];
    const float* Wd = (const float*)d_in[3];
    const float* bd = (const float*)d_in[4];
    const float* Wc = (const float*)d_in[5];
    // bc (d_in[6]) omitted: cancels in |c_i - c_j|
    const int*   s  = (const int*)d_in[7];
    const int*   pv = (const int*)d_in[8];

    char* ws = (char*)d_ws;
    float* hdr = (float*)ws;                                     // 192 f
    float* cP  = (float*)(ws + 1024);                            // 64 KB
    float* cR  = (float*)(ws + 1024 + 65536);                    // 64 KB
    unsigned short* Wepk = (unsigned short*)(ws + 1024 + 2 * 65536);  // 512 KB
    unsigned short* Wdpk = Wepk + (size_t)NH * NF;                    // 512 KB

    prep_kernel<<<32, 256, 0, stream>>>(We, Wd, Wepk, Wdpk, hdr);
    fused_kernel<<<512, 256, 0, stream>>>(X, Wepk, Wdpk, be, bd, Wc, s, pv, cP, cR, hdr);
    pair_fin_kernel<<<dim3(16, 32), 256, 0, stream>>>(cP, cR, hdr, (float*)d_out);
}